// Round 1
// baseline (225.095 us; speedup 1.0000x reference)
//
#include <hip/hip_runtime.h>
#include <hip/hip_bf16.h>

#define NC 10
#define DD 64
#define BB 32
#define SS 16384
#define CHUNK 512
#define NCHUNK (SS / CHUNK)                  // 32
#define NBLK (BB * NCHUNK)                   // 1024
#define TSTR 65                              // merge-tile row stride (pad)
#define TSZ (NC * TSTR)                      // 650
#define OUT_MAIN (2 * BB * NC * DD)          // 40960
#define SEGP_WORDS (NBLK * NC * DD)          // 655,360 f32 partial sums
#define WS_WORDS (SEGP_WORDS + NBLK * NC)    // + 10,240 int counts = 2.54 MiB

// ------------------------------------------------- kernel 1: segment sums ---
// 1024 blocks x 256 thr (4 waves, 4 blocks/CU => all 1024 resident in one
// pass). Lane = dim; the row's label is WAVE-UNIFORM -> v_readlane into SGPR,
// accumulate into 10 REGISTER accumulators via branchless fmac with scalar
// 0/1 mask (s_cmp + s_cselect + v_fmac; SALU runs parallel to VALU).
// NO atomics anywhere: each block stores its private 10x64 partial + 10
// counts to ws; kernel 2 reduces the 32 chunks per batch (2.6 MB, L2-hot).
// Block 0 also zeroes the 128-word init-accumulator tail of out (replaces
// the old zero_kernel launch entirely).
__global__ __launch_bounds__(256, 4) void seg_kernel(
    const float* __restrict__ x, const int* __restrict__ labels,
    float* __restrict__ segp, int* __restrict__ cntp,
    float* __restrict__ out_init)
{
    __shared__ float tiles[4][TSZ];            // 10,400 B, 2-way banks (free)
    __shared__ int wcnt[4][NC];

    const int tid = threadIdx.x;
    const int blk = blockIdx.x;
    const int b = blk >> 5, chunk = blk & 31;
    const long row0 = (long)b * SS + chunk * CHUNK;
    const int w = tid >> 6, lane = tid & 63;

    // wave w owns rows [w*128, (w+1)*128); lane holds labels 2*lane, 2*lane+1
    const int2 lv = ((const int2*)(labels + row0))[w * 64 + lane];
    const float* xr = x + (row0 + w * 128) * DD + lane;

    float acc[NC];
    #pragma unroll
    for (int c = 0; c < NC; ++c) acc[c] = 0.f;

    for (int r1 = 0; r1 < 128; r1 += 8) {
        float v[8];
        #pragma unroll
        for (int u = 0; u < 8; ++u)            // 8 x 256B coalesced in flight
            v[u] = xr[(r1 + u) * DD];
        #pragma unroll
        for (int u = 0; u < 8; ++u) {
            // row r1+u label: component u&1 (const), source lane (r1+u)/2
            const int l = __builtin_amdgcn_readlane(
                (u & 1) ? lv.y : lv.x, (r1 >> 1) + (u >> 1));  // SGPR
            #pragma unroll
            for (int c = 0; c < NC; ++c)       // s_cmp+s_cselect+v_fmac
                acc[c] = fmaf(v[u], (l == c) ? 1.f : 0.f, acc[c]);
        }
    }

    // counts: 2 ballots per cluster over the wave's 128 labels (no atomics)
    #pragma unroll
    for (int c = 0; c < NC; ++c) {
        int n = (int)__popcll(__ballot(lv.x == c))
              + (int)__popcll(__ballot(lv.y == c));
        if (lane == 0) wcnt[w][c] = n;
        tiles[w][c * TSTR + lane] = acc[c];    // reg accs -> wave-private LDS
    }
    __syncthreads();

    for (int i = tid; i < NC * DD; i += 256) { // merge 4 waves -> plain store
        const int c = i >> 6, d = i & 63;
        segp[blk * (NC * DD) + i] =
              tiles[0][c * TSTR + d] + tiles[1][c * TSTR + d]
            + tiles[2][c * TSTR + d] + tiles[3][c * TSTR + d];
    }
    if (tid < NC)
        cntp[blk * NC + tid] = wcnt[0][tid] + wcnt[1][tid]
                             + wcnt[2][tid] + wcnt[3][tid];
    if (blk == 0 && tid < 2 * DD) out_init[tid] = 0.f;
}

// --------------------------------------------------- kernel 2: MLP heads ----
// 64 blocks (b x head) x 1024 thr; reduces the 32 chunk-partials on load
// (coalesced, L2-hot, both heads of a b read the same 80 KB); one float4
// weight stage per thread/layer; waves 0..9 = cluster rows; init sums
// LDS-reduced, 1 global f32 atomic per lane per block into the (pre-zeroed)
// tail.
__global__ __launch_bounds__(1024) void mlp_kernel(
    const float* __restrict__ segp, const int* __restrict__ cntp,
    const float* wm1, const float* bm1, const float* wm2, const float* bm2,
    const float* wm3, const float* bm3,
    const float* wv1, const float* bv1, const float* wv2, const float* bv2,
    const float* wv3, const float* bv3,
    const int* __restrict__ Kptr, float* __restrict__ out)
{
    const int blk = blockIdx.x;                // b*2 + head
    const int b = blk >> 1, head = blk & 1;
    const int tid = threadIdx.x;
    const int w = tid >> 6, lane = tid & 63;

    __shared__ float w_lds[DD * TSTR];         // 16,640 B
    __shared__ float hs[NC][DD];
    __shared__ float hsum[DD];

    const float* Wl[3] = {head ? wv1 : wm1, head ? wv2 : wm2, head ? wv3 : wm3};
    const float* Bl[3] = {head ? bv1 : bm1, head ? bv2 : bm2, head ? bv3 : bm3};

    if (tid < DD) hsum[tid] = 0.f;

    if (w < NC) {                              // reduce 32 chunk partials
        const float* sp = segp + (long)(b * NCHUNK) * (NC * DD) + w * DD + lane;
        const int*   cp = cntp + (b * NCHUNK) * NC + w;
        float s = 0.f; int n = 0;
        #pragma unroll 4
        for (int ch = 0; ch < NCHUNK; ++ch) {
            s += sp[ch * (NC * DD)];           // coalesced across the wave
            n += cp[ch * NC];                  // wave-uniform -> scalar loads
        }
        hs[w][lane] = s / (float)n;
    }
    float val = 0.f;
    const int j = tid >> 4, d0 = (tid & 15) * 4;   // stage target

    #pragma unroll
    for (int layer = 0; layer < 3; ++layer) {
        const float4 wv = ((const float4*)Wl[layer])[tid];  // 1 insn / thread
        const float bias = (w < NC) ? Bl[layer][lane] : 0.f;
        __syncthreads();                       // prev-layer dots (and hs init)
        w_lds[j * TSTR + d0 + 0] = wv.x;
        w_lds[j * TSTR + d0 + 1] = wv.y;
        w_lds[j * TSTR + d0 + 2] = wv.z;
        w_lds[j * TSTR + d0 + 3] = wv.w;
        __syncthreads();                       // W staged
        if (w < NC) {
            float z = bias;
            #pragma unroll
            for (int d = 0; d < DD; ++d)       // hs read = broadcast;
                z += hs[w][d] * w_lds[lane * TSTR + d];  // stride-65 = 2-way
            val = (layer < 2) ? fmaxf(z, 0.f)
                              : (2.f / (1.f + __expf(-z)) - 1.f);
            hs[w][lane] = val;                 // barrier-ordered vs next read
        }
    }
    if (w < NC) {
        out[head * (BB * NC * DD) + (b * NC + w) * DD + lane] = val;
        atomicAdd(&hsum[lane], val);           // LDS atomic, 640 lane-ops
    }
    __syncthreads();
    if (tid < DD)
        unsafeAtomicAdd(&out[OUT_MAIN + head * DD + tid],
                        hsum[tid] / (float)(BB * Kptr[0]));
}

// ------------------------------------- fallback: fused, zero-ws, 32 blocks --
__global__ __launch_bounds__(1024) void fused_fallback_kernel(
    const float* __restrict__ x, const int* __restrict__ labels,
    const float* wm1, const float* bm1, const float* wm2, const float* bm2,
    const float* wm3, const float* bm3,
    const float* wv1, const float* bv1, const float* wv2, const float* bv2,
    const float* wv3, const float* bv3,
    float* __restrict__ out)
{
    __shared__ float ssum[NC * DD];
    __shared__ int scnt[NC];
    __shared__ float hs[NC][DD];
    __shared__ float w_lds[DD * (DD + 1)];

    const int tid = threadIdx.x;
    const int b = blockIdx.x;
    const int wave = tid >> 6, lane = tid & 63;

    for (int i = tid; i < NC * DD; i += 1024) ssum[i] = 0.f;
    if (tid < NC) scnt[tid] = 0;
    __syncthreads();

    const int* lab = labels + b * SS;
    {
        int c_acc[NC];
        #pragma unroll
        for (int c = 0; c < NC; ++c) c_acc[c] = 0;
        for (int i = 0; i < 16; ++i) {
            int l = lab[wave * 1024 + i * 64 + lane];
            #pragma unroll
            for (int c = 0; c < NC; ++c)
                c_acc[c] += (int)__popcll(__ballot(l == c));
        }
        if (lane == 0) {
            #pragma unroll
            for (int c = 0; c < NC; ++c) atomicAdd(&scnt[c], c_acc[c]);
        }
    }

    const float* xb = x + ((long)b * SS + wave * 1024) * DD + lane;
    const int* labw = lab + wave * 1024;
    for (int r = 0; r < 1024; r += 8) {
        float v[8]; int l[8];
        #pragma unroll
        for (int u = 0; u < 8; ++u) { v[u] = xb[(r + u) * DD]; l[u] = labw[r + u]; }
        #pragma unroll
        for (int u = 0; u < 8; ++u) atomicAdd(&ssum[l[u] * DD + lane], v[u]);
    }
    __syncthreads();

    const int c = tid >> 6;
    const bool act = (tid < NC * DD);
    float slot = 0.f;
    if (act) slot = ssum[c * DD + lane] / (float)scnt[c];

    const float* Ws[2][3] = {{wm1, wm2, wm3}, {wv1, wv2, wv3}};
    const float* Bs[2][3] = {{bm1, bm2, bm3}, {bv1, bv2, bv3}};

    #pragma unroll
    for (int head = 0; head < 2; ++head) {
        if (act) hs[c][lane] = slot;
        float val = 0.f;
        #pragma unroll
        for (int layer = 0; layer < 3; ++layer) {
            const float* W = Ws[head][layer];
            for (int i = tid; i < DD * DD; i += 1024)
                w_lds[(i >> 6) * (DD + 1) + (i & 63)] = W[i];
            __syncthreads();
            if (act) {
                float z = Bs[head][layer][lane];
                #pragma unroll
                for (int d = 0; d < DD; ++d)
                    z += hs[c][d] * w_lds[lane * (DD + 1) + d];
                val = (layer < 2) ? fmaxf(z, 0.f)
                                  : (2.f / (1.f + __expf(-z)) - 1.f);
            }
            __syncthreads();
            if (act) hs[c][lane] = val;
        }
        if (act) out[head * (BB * NC * DD) + (b * NC + c) * DD + lane] = val;
        __syncthreads();
    }
}

__global__ __launch_bounds__(128) void init_fallback_kernel(
    const float* __restrict__ outro, const int* __restrict__ Kptr,
    float* __restrict__ out)
{
    const int t = threadIdx.x;
    const int head = t >> 6, lane = t & 63;
    const float* src = outro + head * (BB * NC * DD) + lane;
    float s = 0.f;
    for (int r = 0; r < BB * NC; ++r) s += src[r * DD];
    out[OUT_MAIN + t] = s / (float)(BB * Kptr[0]);
}

extern "C" void kernel_launch(void* const* d_in, const int* in_sizes, int n_in,
                              void* d_out, int out_size, void* d_ws, size_t ws_size,
                              hipStream_t stream)
{
    const float* x      = (const float*)d_in[0];
    const int*   labels = (const int*)d_in[1];
    const int*   K      = (const int*)d_in[2];
    const float* wm1 = (const float*)d_in[3];
    const float* bm1 = (const float*)d_in[4];
    const float* wm2 = (const float*)d_in[5];
    const float* bm2 = (const float*)d_in[6];
    const float* wm3 = (const float*)d_in[7];
    const float* bm3 = (const float*)d_in[8];
    const float* wv1 = (const float*)d_in[9];
    const float* bv1 = (const float*)d_in[10];
    const float* wv2 = (const float*)d_in[11];
    const float* bv2 = (const float*)d_in[12];
    const float* wv3 = (const float*)d_in[13];
    const float* bv3 = (const float*)d_in[14];
    float* out = (float*)d_out;

    if (ws_size >= (size_t)WS_WORDS * 4) {
        float* segp = (float*)d_ws;
        int*   cntp = (int*)((char*)d_ws + (size_t)SEGP_WORDS * 4);
        seg_kernel<<<NBLK, 256, 0, stream>>>(x, labels, segp, cntp,
                                             out + OUT_MAIN);
        mlp_kernel<<<2 * BB, 1024, 0, stream>>>(
            segp, cntp,
            wm1, bm1, wm2, bm2, wm3, bm3,
            wv1, bv1, wv2, bv2, wv3, bv3, K, out);
    } else {
        fused_fallback_kernel<<<BB, 1024, 0, stream>>>(
            x, labels,
            wm1, bm1, wm2, bm2, wm3, bm3,
            wv1, bv1, wv2, bv2, wv3, bv3, out);
        init_fallback_kernel<<<1, 128, 0, stream>>>((const float*)d_out, K, out);
    }
}